// Round 3
// baseline (1238.553 us; speedup 1.0000x reference)
//
#include <hip/hip_runtime.h>

#define NN 50000
#define EE 1600000
#define DD 128
#define CC 10
#define LLAY 4
#define GG 512
#define GD (GG*DD)
#define NB 196           // ceil(NN/256) coarse buckets
#define BK_EDGES 6400    // edges per binA block

static constexpr float BN_EPS = 1e-5f;
static constexpr float INV_N = 1.0f / (float)NN;

typedef __bf16 bf16x8 __attribute__((ext_vector_type(8)));
typedef float f32x4 __attribute__((ext_vector_type(4)));

static __device__ __forceinline__ float bflo(unsigned u){ return __uint_as_float(u << 16); }
static __device__ __forceinline__ float bfhi(unsigned u){ return __uint_as_float(u & 0xffff0000u); }
static __device__ __forceinline__ unsigned short f2bf(float f){
    unsigned u = __float_as_uint(f);
    return (unsigned short)((u + 0x7fffu + ((u >> 16) & 1u)) >> 16);   // RNE
}
static __device__ __forceinline__ unsigned packbf(float a, float b){
    return (unsigned)f2bf(a) | ((unsigned)f2bf(b) << 16);
}
static __device__ __forceinline__ bf16x8 ldfrag(const unsigned short* p){
    union { uint4 u; bf16x8 b; } t; t.u = *(const uint4*)p; return t.b;
}

// ---------------- setup kernels ----------------

__global__ void zero_k(float* p, int n){
    int i = blockIdx.x * 256 + threadIdx.x;
    if (i < n) p[i] = 0.f;
}

// x (fp32) -> slab-layout bf16 h:  hs[s][n][j], s=f2>>3, j=f2&7 (f2 = uint-pair idx)
__global__ void convx_k(const float2* __restrict__ x2, unsigned* __restrict__ hs){
    int i = blockIdx.x * 256 + threadIdx.x;   // grid covers NN*64 exactly
    float2 v = x2[i];
    int n = i >> 6, f2 = i & 63;
    hs[(f2 >> 3) * (NN * 8) + n * 8 + (f2 & 7)] = packbf(v.x, v.y);
}

// all 8 weight matrices -> bf16 W^T [j][k] in ws
__global__ void wprep_k(const float* __restrict__ W1, const float* __restrict__ W2,
                        unsigned short* __restrict__ Wtall){
    int idx = blockIdx.x * 256 + threadIdx.x;         // < 8*16384
    int mat = idx >> 14; int rr = idx & 16383;
    int k = rr >> 7; int j = rr & 127;
    const float* Wsrc = (mat < 4) ? (W1 + mat * 16384) : (W2 + (mat - 4) * 16384);
    Wtall[mat * 16384 + j * 128 + k] = f2bf(Wsrc[k * 128 + j]);
}

__global__ void hist_k(const int* __restrict__ dstA, const int* __restrict__ batch,
                       int* __restrict__ cnt, int* __restrict__ gcnt){
    int i = blockIdx.x * 256 + threadIdx.x;
    if (i < EE) atomicAdd(&cnt[dstA[i]], 1);
    if (i < NN) atomicAdd(&gcnt[batch[i]], 1);
}

__global__ __launch_bounds__(256) void scan1_k(const int* __restrict__ cnt, int* __restrict__ rp,
                                               int* __restrict__ bsums){
    __shared__ int lds[256];
    int t = threadIdx.x; int base = blockIdx.x * 1024 + t * 4;
    int v0 = (base + 0 < NN) ? cnt[base + 0] : 0;
    int v1 = (base + 1 < NN) ? cnt[base + 1] : 0;
    int v2 = (base + 2 < NN) ? cnt[base + 2] : 0;
    int v3 = (base + 3 < NN) ? cnt[base + 3] : 0;
    int s = v0 + v1 + v2 + v3;
    lds[t] = s; __syncthreads();
    for (int o = 1; o < 256; o <<= 1){
        int xv = 0; if (t >= o) xv = lds[t - o];
        __syncthreads(); lds[t] += xv; __syncthreads();
    }
    int excl = lds[t] - s;
    if (t == 255) bsums[blockIdx.x] = lds[255];
    int run = excl;
    if (base + 0 < NN) rp[base + 0] = run; run += v0;
    if (base + 1 < NN) rp[base + 1] = run; run += v1;
    if (base + 2 < NN) rp[base + 2] = run; run += v2;
    if (base + 3 < NN) rp[base + 3] = run;
}

__global__ __launch_bounds__(256) void scan2_k(int* __restrict__ bsums, int nb,
                                               const int* __restrict__ gcnt, int* __restrict__ gstart){
    __shared__ int lds[256];
    int t = threadIdx.x;
    int v0 = gcnt[2 * t], v1 = gcnt[2 * t + 1];
    int s = v0 + v1;
    lds[t] = s; __syncthreads();
    for (int o = 1; o < 256; o <<= 1){
        int xv = 0; if (t >= o) xv = lds[t - o];
        __syncthreads(); lds[t] += xv; __syncthreads();
    }
    int excl = lds[t] - s;
    gstart[2 * t] = excl; gstart[2 * t + 1] = excl + v0;
    if (t == 255) gstart[GG] = lds[255];
    __syncthreads();
    int sv = (t < nb) ? bsums[t] : 0;
    lds[t] = sv; __syncthreads();
    for (int o = 1; o < 256; o <<= 1){
        int xv = 0; if (t >= o) xv = lds[t - o];
        __syncthreads(); lds[t] += xv; __syncthreads();
    }
    if (t < nb) bsums[t] = lds[t] - sv;
}

__global__ void scan3_k(int* __restrict__ rp, const int* __restrict__ bsums,
                        int* __restrict__ bucketCur){
    int i = blockIdx.x * 256 + threadIdx.x;
    if (i < NN){
        int v = rp[i] + bsums[i >> 10];
        rp[i] = v;
        if ((i & 255) == 0) bucketCur[i >> 8] = v;   // bucket write allocator base
    }
    if (i == 0) rp[NN] = EE;
}

// ---- two-phase edge binning (replaces random scatter) ----
// Pass A: bin edges into NB coarse buckets (256 dst-nodes each), contiguous runs.
__global__ __launch_bounds__(256) void binA_k(const int* __restrict__ srcA,
                                              const int* __restrict__ dstA,
                                              int* __restrict__ bucketCur,
                                              unsigned* __restrict__ binned){
    __shared__ int cnt[NB], bas[NB], off[NB];
    int tid = threadIdx.x;
    if (tid < NB){ cnt[tid] = 0; off[tid] = 0; }
    __syncthreads();
    int e0 = blockIdx.x * BK_EDGES;
    for (int i = tid; i < BK_EDGES; i += 256){
        int e = e0 + i;
        if (e < EE) atomicAdd(&cnt[dstA[e] >> 8], 1);
    }
    __syncthreads();
    if (tid < NB && cnt[tid] > 0) bas[tid] = atomicAdd(&bucketCur[tid], cnt[tid]);
    __syncthreads();
    for (int i = tid; i < BK_EDGES; i += 256){
        int e = e0 + i;
        if (e < EE){
            int d = dstA[e]; int b = d >> 8;
            int p = bas[b] + atomicAdd(&off[b], 1);
            binned[p] = (unsigned)srcA[e] | ((unsigned)(d & 255) << 17);  // src<2^17
        }
    }
}

// Pass B: exact placement within each bucket's contiguous [rp] range (L2-local writes).
__global__ __launch_bounds__(256) void binB_k(const unsigned* __restrict__ binned,
                                              const int* __restrict__ rp,
                                              int* __restrict__ ssort){
    __shared__ int srp[256]; __shared__ int curl[256];
    int b = blockIdx.x, tid = threadIdx.x;
    int nb0 = b * 256;
    int nmax = NN - nb0; if (nmax > 256) nmax = 256;
    if (tid < nmax) srp[tid] = rp[nb0 + tid];
    curl[tid] = 0;
    __syncthreads();
    int base = rp[nb0];
    int end  = rp[(nb0 + 256 < NN) ? nb0 + 256 : NN];
    for (int i = base + tid; i < end; i += 256){
        unsigned u = binned[i];
        int dl = (int)(u >> 17); int src = (int)(u & 0x1FFFFu);
        int pos = srp[dl] + atomicAdd(&curl[dl], 1);
        ssort[pos] = src;
    }
}

// ---------------- per-layer kernels ----------------

// z = h + sum_{in-edges} h[src], slab-sliced gather (XCD-affine via blockIdx&7).
// Wave = one (node, slab): 8 edge-slots x 8 feature-lanes (32B/edge/slab).
__global__ __launch_bounds__(256) void agg_k(const unsigned* __restrict__ hs,
                                             const int* __restrict__ rp,
                                             const int* __restrict__ ssort,
                                             unsigned* __restrict__ z32){
    int s = blockIdx.x & 7;            // slab == XCD under %8 round-robin dispatch
    int ng = blockIdx.x >> 3;
    int wv = threadIdx.x >> 6, lane = threadIdx.x & 63;
    int n = ng * 4 + wv;               // grid = 8 * (NN/4): n < NN exactly
    int eo = lane >> 3, j = lane & 7;
    const unsigned* hsl = hs + s * (NN * 8);
    float ax = 0.f, ay = 0.f;
    int e1 = rp[n + 1];
    int e = rp[n] + eo;
    for (; e + 8 < e1; e += 16){       // 2 independent gathers in flight
        int s0 = ssort[e], s1 = ssort[e + 8];
        unsigned u0 = hsl[s0 * 8 + j];
        unsigned u1 = hsl[s1 * 8 + j];
        ax += bflo(u0); ay += bfhi(u0);
        ax += bflo(u1); ay += bfhi(u1);
    }
    if (e < e1){
        int s0 = ssort[e];
        unsigned u0 = hsl[s0 * 8 + j];
        ax += bflo(u0); ay += bfhi(u0);
    }
    ax += __shfl_xor(ax, 8);  ay += __shfl_xor(ay, 8);
    ax += __shfl_xor(ax, 16); ay += __shfl_xor(ay, 16);
    ax += __shfl_xor(ax, 32); ay += __shfl_xor(ay, 32);
    if (eo == 0){
        unsigned self = hsl[n * 8 + j];
        z32[n * 64 + s * 8 + j] = packbf(ax + bflo(self), ay + bfhi(self));
    }
}

// C[N,128] = opt_relu_bn(A[N,128]) @ W[128,128] + bias, bf16 MFMA 16x16x32
template<int TR>
__global__ __launch_bounds__(256) void gemm_k(const unsigned* __restrict__ A32,
                                              const unsigned short* __restrict__ Wtg,
                                              const float* __restrict__ bias,
                                              unsigned short* __restrict__ Cst,
                                              const float* __restrict__ stats,
                                              const float* __restrict__ gma,
                                              const float* __restrict__ bta,
                                              float* __restrict__ zstats){
    __shared__ __align__(16) unsigned short Wl[128 * 128];  // [j][k] 32KB
    __shared__ __align__(16) unsigned short As[128 * 64];   // [row][k-half] 16KB
    __shared__ float sl[128], tl[128];
    int tid = threadIdx.x;
    if (blockIdx.x == 0 && zstats) zstats[tid] = 0.f;       // zero stats for next kernel
    {
        const uint4* src = (const uint4*)Wtg; uint4* dst = (uint4*)Wl;
        #pragma unroll
        for (int i = 0; i < 8; i++) dst[tid + 256 * i] = src[tid + 256 * i];
    }
    if (TR && tid < 128){
        float mean = stats[tid] * INV_N;
        float q    = stats[128 + tid] * INV_N;
        float inv  = rsqrtf(q - mean * mean + BN_EPS);
        float s    = gma[tid] * inv;
        sl[tid] = s; tl[tid] = bta[tid] - mean * s;
    }
    __syncthreads();

    f32x4 acc[2][8];
    #pragma unroll
    for (int a = 0; a < 2; a++)
        #pragma unroll
        for (int b = 0; b < 8; b++) acc[a][b] = (f32x4){0.f, 0.f, 0.f, 0.f};

    int wv = tid >> 6, lane = tid & 63;
    int rowbase = blockIdx.x * 128;
    int r = tid >> 1, koU = (tid & 1) * 16;

    for (int kh = 0; kh < 2; ++kh){
        if (kh) __syncthreads();
        uint4 v[4];
        int grow = rowbase + r;
        if (grow < NN){
            const uint4* p = (const uint4*)(A32 + grow * 64 + kh * 32 + koU);
            #pragma unroll
            for (int j = 0; j < 4; j++) v[j] = p[j];
        } else {
            #pragma unroll
            for (int j = 0; j < 4; j++) v[j] = make_uint4(0, 0, 0, 0);
        }
        if (TR){
            #pragma unroll
            for (int j = 0; j < 4; j++){
                unsigned* pu = (unsigned*)&v[j];
                #pragma unroll
                for (int c = 0; c < 4; c++){
                    int k = kh * 64 + koU * 2 + j * 8 + c * 2;
                    float f0 = fmaxf(bflo(pu[c]) * sl[k] + tl[k], 0.f);
                    float f1 = fmaxf(bfhi(pu[c]) * sl[k + 1] + tl[k + 1], 0.f);
                    pu[c] = packbf(f0, f1);
                }
            }
        }
        {
            uint4* dst = ((uint4*)As) + r * 8 + (tid & 1) * 4;
            #pragma unroll
            for (int j = 0; j < 4; j++) dst[j] = v[j];
        }
        __syncthreads();
        #pragma unroll
        for (int kc = 0; kc < 2; ++kc){
            int kof = kc * 32 + ((lane >> 4) * 8);
            bf16x8 a0 = ldfrag(&As[(wv * 32 +      (lane & 15)) * 64 + kof]);
            bf16x8 a1 = ldfrag(&As[(wv * 32 + 16 + (lane & 15)) * 64 + kof]);
            int wk = kh * 64 + kof;
            #pragma unroll
            for (int ct = 0; ct < 8; ++ct){
                bf16x8 b = ldfrag(&Wl[(ct * 16 + (lane & 15)) * 128 + wk]);
                acc[0][ct] = __builtin_amdgcn_mfma_f32_16x16x32_bf16(a0, b, acc[0][ct], 0, 0, 0);
                acc[1][ct] = __builtin_amdgcn_mfma_f32_16x16x32_bf16(a1, b, acc[1][ct], 0, 0, 0);
            }
        }
    }
    int cl = lane & 15, rq = lane >> 4;
    #pragma unroll
    for (int ct = 0; ct < 8; ++ct){
        float bv = bias[ct * 16 + cl];
        #pragma unroll
        for (int rt = 0; rt < 2; ++rt){
            #pragma unroll
            for (int rr2 = 0; rr2 < 4; ++rr2){
                int grow = rowbase + wv * 32 + rt * 16 + rq * 4 + rr2;
                if (grow < NN) Cst[grow * 128 + ct * 16 + cl] = f2bf(acc[rt][ct][rr2] + bv);
            }
        }
    }
}

// column sums / sumsq over N rows (bf16 input, standard [n][64] layout)
__global__ __launch_bounds__(256) void stats_k(const unsigned* __restrict__ z32,
                                               float* __restrict__ stats){
    __shared__ float sd[1024];
    int tid = threadIdx.x; int c = tid & 63; int rs = tid >> 6;
    float s1x = 0, s1y = 0, s2x = 0, s2y = 0;
    for (int row = blockIdx.x * 4 + rs; row < NN; row += 512 * 4){
        unsigned u = z32[row * 64 + c];
        float f0 = bflo(u), f1 = bfhi(u);
        s1x += f0; s1y += f1; s2x += f0 * f0; s2y += f1 * f1;
    }
    sd[tid] = s1x; sd[256 + tid] = s1y; sd[512 + tid] = s2x; sd[768 + tid] = s2y;
    __syncthreads();
    if (tid < 64){
        float a0 = 0, a1 = 0, a2 = 0, a3 = 0;
        #pragma unroll
        for (int k2 = 0; k2 < 4; k2++){
            int t = tid + 64 * k2;
            a0 += sd[t]; a1 += sd[256 + t]; a2 += sd[512 + t]; a3 += sd[768 + t];
        }
        atomicAdd(&stats[2 * tid],       a0); atomicAdd(&stats[2 * tid + 1],       a1);
        atomicAdd(&stats[128 + 2 * tid], a2); atomicAdd(&stats[128 + 2 * tid + 1], a3);
    }
}

// h = relu(bn(z)) -> slab layout hs
__global__ void ew_k(const unsigned* __restrict__ z32, const float* __restrict__ stats,
                     const float* __restrict__ g, const float* __restrict__ b,
                     unsigned* __restrict__ hs){
    int i = blockIdx.x * 256 + threadIdx.x;    // grid covers NN*64 exactly
    int c = (i & 63) * 2;
    unsigned u = z32[i];
    float m0 = stats[c] * INV_N,     q0 = stats[128 + c] * INV_N;
    float inv0 = rsqrtf(q0 - m0 * m0 + BN_EPS);
    float s0 = g[c] * inv0, t0 = b[c] - m0 * s0;
    float m1 = stats[c + 1] * INV_N, q1 = stats[129 + c] * INV_N;
    float inv1 = rsqrtf(q1 - m1 * m1 + BN_EPS);
    float s1 = g[c + 1] * inv1, t1 = b[c + 1] - m1 * s1;
    int n = i >> 6, f2 = i & 63;
    hs[(f2 >> 3) * (NN * 8) + n * 8 + (f2 & 7)] =
        packbf(fmaxf(bflo(u) * s0 + t0, 0.f), fmaxf(bfhi(u) * s1 + t1, 0.f));
}

// per-graph segment sum of slab-layout bf16 h -> pooled (fp32)
__global__ __launch_bounds__(256) void pool_k(const unsigned* __restrict__ hs,
                                              const int* __restrict__ gstart,
                                              float* __restrict__ outp){
    __shared__ float sd[512];
    int g = blockIdx.x; int tid = threadIdx.x; int f2 = tid & 63, rs = tid >> 6;
    int sOff = (f2 >> 3) * (NN * 8) + (f2 & 7);
    int s = gstart[g], e = gstart[g + 1];
    float a0 = 0, a1 = 0;
    for (int n = s + rs; n < e; n += 4){
        unsigned u = hs[sOff + n * 8];
        a0 += bflo(u); a1 += bfhi(u);
    }
    sd[tid] = a0; sd[256 + tid] = a1; __syncthreads();
    if (tid < 64){
        float r0 = 0, r1 = 0;
        #pragma unroll
        for (int k2 = 0; k2 < 4; k2++){ r0 += sd[tid + 64 * k2]; r1 += sd[256 + tid + 64 * k2]; }
        outp[g * 128 + 2 * tid] = r0; outp[g * 128 + 2 * tid + 1] = r1;
    }
}

// pooled[0] from fp32 x (exact)
__global__ __launch_bounds__(256) void poolx_k(const float* __restrict__ x,
                                               const int* __restrict__ gstart,
                                               float* __restrict__ outp){
    __shared__ float sd[256];
    int g = blockIdx.x; int tid = threadIdx.x; int c = tid & 127, rs = tid >> 7;
    int s = gstart[g], e = gstart[g + 1];
    float a = 0;
    for (int n = s + rs; n < e; n += 2) a += x[n * 128 + c];
    sd[tid] = a; __syncthreads();
    if (tid < 128) outp[g * 128 + tid] = sd[tid] + sd[tid + 128];
}

// logits = sum_i pooled_i @ fcW_i + fcb_i ; out = log_softmax(logits)
__global__ __launch_bounds__(64) void final_k(const float* __restrict__ pooled,
                                              const float* __restrict__ fcW,
                                              const float* __restrict__ fcb,
                                              float* __restrict__ out){
    int g = blockIdx.x, l = threadIdx.x;
    float p0[5], p1[5];
    #pragma unroll
    for (int i = 0; i < 5; i++){
        p0[i] = pooled[i * GD + g * 128 + l];
        p1[i] = pooled[i * GD + g * 128 + 64 + l];
    }
    float lg[10];
    #pragma unroll
    for (int c2 = 0; c2 < 10; c2++){
        float s = 0;
        #pragma unroll
        for (int i = 0; i < 5; i++){
            s += p0[i] * fcW[(i * 128 + l) * 10 + c2];
            s += p1[i] * fcW[(i * 128 + 64 + l) * 10 + c2];
        }
        #pragma unroll
        for (int off = 32; off >= 1; off >>= 1) s += __shfl_down(s, off);
        lg[c2] = s;
    }
    if (l == 0){
        #pragma unroll
        for (int c2 = 0; c2 < 10; c2++){
            float bs = 0;
            #pragma unroll
            for (int i = 0; i < 5; i++) bs += fcb[i * 10 + c2];
            lg[c2] += bs;
        }
        float mx = lg[0];
        #pragma unroll
        for (int c2 = 1; c2 < 10; c2++) mx = fmaxf(mx, lg[c2]);
        float se = 0;
        #pragma unroll
        for (int c2 = 0; c2 < 10; c2++) se += expf(lg[c2] - mx);
        float lse = mx + logf(se);
        #pragma unroll
        for (int c2 = 0; c2 < 10; c2++) out[g * 10 + c2] = lg[c2] - lse;
    }
}

// ---------------- launch ----------------

extern "C" void kernel_launch(void* const* d_in, const int* in_sizes, int n_in,
                              void* d_out, int out_size, void* d_ws, size_t ws_size,
                              hipStream_t stream){
    (void)in_sizes; (void)n_in; (void)out_size; (void)ws_size;
    const float* x     = (const float*)d_in[0];
    const int*   ei    = (const int*)d_in[1];
    const int*   batch = (const int*)d_in[2];
    const float* cW1   = (const float*)d_in[4];
    const float* cb1   = (const float*)d_in[5];
    const float* cbng  = (const float*)d_in[6];
    const float* cbnb  = (const float*)d_in[7];
    const float* cW2   = (const float*)d_in[8];
    const float* cb2   = (const float*)d_in[9];
    const float* bng   = (const float*)d_in[10];
    const float* bnb   = (const float*)d_in[11];
    const float* fcW   = (const float*)d_in[12];
    const float* fcb   = (const float*)d_in[13];

    char* base = (char*)d_ws;
    size_t off = 0;
    auto alloc = [&](size_t bytes) -> void* {
        void* p = base + off;
        off = (off + bytes + 255) & ~(size_t)255;
        return p;
    };
    unsigned*       hS     = (unsigned*)alloc((size_t)NN * 64 * 4);   // slab layout h
    unsigned*       zA     = (unsigned*)alloc((size_t)NN * 64 * 4);
    unsigned*       zB     = (unsigned*)alloc((size_t)NN * 64 * 4);
    unsigned short* Wtall  = (unsigned short*)alloc(8 * 16384 * 2);
    int*            ssort  = (int*)alloc((size_t)EE * 4);
    int*            rp     = (int*)alloc((NN + 1) * 4);
    int*            bsums  = (int*)alloc(256 * 4);
    int*            gstart = (int*)alloc((GG + 1) * 4);
    int*            bucketCur = (int*)alloc(NB * 4);
    // ---- contiguous zero region: cnt, gcnt, pooled ----
    int*            cnt    = (int*)alloc(NN * 4);
    int*            gcnt   = (int*)alloc(GG * 4);
    float*          pooled = (float*)alloc((size_t)5 * GD * 4);
    // ---------------------------------------------------
    float*          stats1 = (float*)alloc(256 * 4);
    float*          stats2 = (float*)alloc(256 * 4);
    unsigned*       binned = zA;   // alias: binned used only before layer loop

    int zwords = (int)(((char*)(pooled + 5 * GD) - (char*)cnt) / 4);

    zero_k<<<(zwords + 255) / 256, 256, 0, stream>>>((float*)cnt, zwords);
    convx_k<<<NN * 64 / 256, 256, 0, stream>>>((const float2*)x, hS);
    wprep_k<<<512, 256, 0, stream>>>(cW1, cW2, Wtall);
    hist_k<<<EE / 256, 256, 0, stream>>>(ei + EE, batch, cnt, gcnt);
    scan1_k<<<49, 256, 0, stream>>>(cnt, rp, bsums);
    scan2_k<<<1, 256, 0, stream>>>(bsums, 49, gcnt, gstart);
    scan3_k<<<(NN + 255) / 256, 256, 0, stream>>>(rp, bsums, bucketCur);
    binA_k<<<(EE + BK_EDGES - 1) / BK_EDGES, 256, 0, stream>>>(ei, ei + EE, bucketCur, binned);
    binB_k<<<NB, 256, 0, stream>>>(binned, rp, ssort);
    poolx_k<<<GG, 256, 0, stream>>>(x, gstart, pooled);

    const int gemmGrid = (NN + 127) / 128;
    for (int i = 0; i < LLAY; i++){
        agg_k<<<8 * (NN / 4), 256, 0, stream>>>(hS, rp, ssort, zA);
        gemm_k<0><<<gemmGrid, 256, 0, stream>>>(zA, Wtall + i * 16384, cb1 + i * 128,
                                                (unsigned short*)zB,
                                                nullptr, nullptr, nullptr, stats1);
        stats_k<<<512, 256, 0, stream>>>(zB, stats1);
        gemm_k<1><<<gemmGrid, 256, 0, stream>>>(zB, Wtall + (4 + i) * 16384, cb2 + i * 128,
                                                (unsigned short*)zA,
                                                stats1, cbng + i * 128, cbnb + i * 128, stats2);
        stats_k<<<512, 256, 0, stream>>>(zA, stats2);
        ew_k<<<NN * 64 / 256, 256, 0, stream>>>(zA, stats2, bng + i * 128, bnb + i * 128, hS);
        pool_k<<<GG, 256, 0, stream>>>(hS, gstart, pooled + (size_t)(i + 1) * GD);
    }
    final_k<<<GG, 64, 0, stream>>>(pooled, fcW, fcb, (float*)d_out);
}

// Round 4
// 714.718 us; speedup vs baseline: 1.7329x; 1.7329x over previous
//
#include <hip/hip_runtime.h>

#define NN 50000
#define EE 1600000
#define DD 128
#define CC 10
#define LLAY 4
#define GG 512
#define GD (GG*DD)
#define NB 196           // ceil(NN/256) coarse buckets
#define BK_EDGES 6400    // edges per binA block

static constexpr float BN_EPS = 1e-5f;
static constexpr float INV_N = 1.0f / (float)NN;

typedef __bf16 bf16x8 __attribute__((ext_vector_type(8)));
typedef float f32x4 __attribute__((ext_vector_type(4)));

static __device__ __forceinline__ float bflo(unsigned u){ return __uint_as_float(u << 16); }
static __device__ __forceinline__ float bfhi(unsigned u){ return __uint_as_float(u & 0xffff0000u); }
static __device__ __forceinline__ unsigned short f2bf(float f){
    unsigned u = __float_as_uint(f);
    return (unsigned short)((u + 0x7fffu + ((u >> 16) & 1u)) >> 16);   // RNE
}
static __device__ __forceinline__ unsigned packbf(float a, float b){
    return (unsigned)f2bf(a) | ((unsigned)f2bf(b) << 16);
}
static __device__ __forceinline__ bf16x8 ldfrag(const unsigned short* p){
    union { uint4 u; bf16x8 b; } t; t.u = *(const uint4*)p; return t.b;
}

// ---------------- setup kernels ----------------

__global__ void zero_k(float* p, int n){
    int i = blockIdx.x * 256 + threadIdx.x;
    if (i < n) p[i] = 0.f;
}

// x (fp32) -> [n][64] packed bf16-pair layout
__global__ void convx_k(const float2* __restrict__ x2, unsigned* __restrict__ h32){
    int i = blockIdx.x * 256 + threadIdx.x;   // grid covers NN*64 exactly
    float2 v = x2[i];
    h32[i] = packbf(v.x, v.y);
}

// all 8 weight matrices -> bf16 W^T [j][k] in ws
__global__ void wprep_k(const float* __restrict__ W1, const float* __restrict__ W2,
                        unsigned short* __restrict__ Wtall){
    int idx = blockIdx.x * 256 + threadIdx.x;         // < 8*16384
    int mat = idx >> 14; int rr = idx & 16383;
    int k = rr >> 7; int j = rr & 127;
    const float* Wsrc = (mat < 4) ? (W1 + mat * 16384) : (W2 + (mat - 4) * 16384);
    Wtall[mat * 16384 + j * 128 + k] = f2bf(Wsrc[k * 128 + j]);
}

__global__ void hist_k(const int* __restrict__ dstA, const int* __restrict__ batch,
                       int* __restrict__ cnt, int* __restrict__ gcnt){
    int i = blockIdx.x * 256 + threadIdx.x;
    if (i < EE) atomicAdd(&cnt[dstA[i]], 1);
    if (i < NN) atomicAdd(&gcnt[batch[i]], 1);
}

__global__ __launch_bounds__(256) void scan1_k(const int* __restrict__ cnt, int* __restrict__ rp,
                                               int* __restrict__ bsums){
    __shared__ int lds[256];
    int t = threadIdx.x; int base = blockIdx.x * 1024 + t * 4;
    int v0 = (base + 0 < NN) ? cnt[base + 0] : 0;
    int v1 = (base + 1 < NN) ? cnt[base + 1] : 0;
    int v2 = (base + 2 < NN) ? cnt[base + 2] : 0;
    int v3 = (base + 3 < NN) ? cnt[base + 3] : 0;
    int s = v0 + v1 + v2 + v3;
    lds[t] = s; __syncthreads();
    for (int o = 1; o < 256; o <<= 1){
        int xv = 0; if (t >= o) xv = lds[t - o];
        __syncthreads(); lds[t] += xv; __syncthreads();
    }
    int excl = lds[t] - s;
    if (t == 255) bsums[blockIdx.x] = lds[255];
    int run = excl;
    if (base + 0 < NN) rp[base + 0] = run; run += v0;
    if (base + 1 < NN) rp[base + 1] = run; run += v1;
    if (base + 2 < NN) rp[base + 2] = run; run += v2;
    if (base + 3 < NN) rp[base + 3] = run;
}

__global__ __launch_bounds__(256) void scan2_k(int* __restrict__ bsums, int nb,
                                               const int* __restrict__ gcnt, int* __restrict__ gstart){
    __shared__ int lds[256];
    int t = threadIdx.x;
    int v0 = gcnt[2 * t], v1 = gcnt[2 * t + 1];
    int s = v0 + v1;
    lds[t] = s; __syncthreads();
    for (int o = 1; o < 256; o <<= 1){
        int xv = 0; if (t >= o) xv = lds[t - o];
        __syncthreads(); lds[t] += xv; __syncthreads();
    }
    int excl = lds[t] - s;
    gstart[2 * t] = excl; gstart[2 * t + 1] = excl + v0;
    if (t == 255) gstart[GG] = lds[255];
    __syncthreads();
    int sv = (t < nb) ? bsums[t] : 0;
    lds[t] = sv; __syncthreads();
    for (int o = 1; o < 256; o <<= 1){
        int xv = 0; if (t >= o) xv = lds[t - o];
        __syncthreads(); lds[t] += xv; __syncthreads();
    }
    if (t < nb) bsums[t] = lds[t] - sv;
}

__global__ void scan3_k(int* __restrict__ rp, const int* __restrict__ bsums,
                        int* __restrict__ bucketCur){
    int i = blockIdx.x * 256 + threadIdx.x;
    if (i < NN){
        int v = rp[i] + bsums[i >> 10];
        rp[i] = v;
        if ((i & 255) == 0) bucketCur[i >> 8] = v;   // bucket write allocator base
    }
    if (i == 0) rp[NN] = EE;
}

// ---- two-phase edge binning (replaces random scatter) ----
__global__ __launch_bounds__(256) void binA_k(const int* __restrict__ srcA,
                                              const int* __restrict__ dstA,
                                              int* __restrict__ bucketCur,
                                              unsigned* __restrict__ binned){
    __shared__ int cnt[NB], bas[NB], off[NB];
    int tid = threadIdx.x;
    if (tid < NB){ cnt[tid] = 0; off[tid] = 0; }
    __syncthreads();
    int e0 = blockIdx.x * BK_EDGES;
    for (int i = tid; i < BK_EDGES; i += 256){
        int e = e0 + i;
        if (e < EE) atomicAdd(&cnt[dstA[e] >> 8], 1);
    }
    __syncthreads();
    if (tid < NB && cnt[tid] > 0) bas[tid] = atomicAdd(&bucketCur[tid], cnt[tid]);
    __syncthreads();
    for (int i = tid; i < BK_EDGES; i += 256){
        int e = e0 + i;
        if (e < EE){
            int d = dstA[e]; int b = d >> 8;
            int p = bas[b] + atomicAdd(&off[b], 1);
            binned[p] = (unsigned)srcA[e] | ((unsigned)(d & 255) << 17);  // src<2^17
        }
    }
}

__global__ __launch_bounds__(256) void binB_k(const unsigned* __restrict__ binned,
                                              const int* __restrict__ rp,
                                              int* __restrict__ ssort){
    __shared__ int srp[256]; __shared__ int curl[256];
    int b = blockIdx.x, tid = threadIdx.x;
    int nb0 = b * 256;
    int nmax = NN - nb0; if (nmax > 256) nmax = 256;
    if (tid < nmax) srp[tid] = rp[nb0 + tid];
    curl[tid] = 0;
    __syncthreads();
    int base = rp[nb0];
    int end  = rp[(nb0 + 256 < NN) ? nb0 + 256 : NN];
    for (int i = base + tid; i < end; i += 256){
        unsigned u = binned[i];
        int dl = (int)(u >> 17); int src = (int)(u & 0x1FFFFu);
        int pos = srp[dl] + atomicAdd(&curl[dl], 1);
        ssort[pos] = src;
    }
}

// ---------------- per-layer kernels ----------------

// z = h + sum_{in-edges} h[src]; block 0 also zeroes stats1 for the next gemm.
__global__ __launch_bounds__(256) void agg_k(const unsigned* __restrict__ h32,
                                             const int* __restrict__ rp,
                                             const int* __restrict__ ssort,
                                             unsigned* __restrict__ z32,
                                             float* __restrict__ zstats){
    int tid = threadIdx.x;
    if (blockIdx.x == 0) zstats[tid] = 0.f;
    int n = blockIdx.x * 4 + (tid >> 6);  // grid*4 == NN exactly
    int lane = tid & 63;
    unsigned self = h32[n * 64 + lane];
    float ax = bflo(self), ay = bfhi(self);
    int e  = __builtin_amdgcn_readfirstlane(rp[n]);
    int e1 = __builtin_amdgcn_readfirstlane(rp[n + 1]);
    for (; e + 3 < e1; e += 4){
        int s0 = ssort[e], s1 = ssort[e + 1], s2 = ssort[e + 2], s3 = ssort[e + 3];
        unsigned u0 = h32[s0 * 64 + lane];
        unsigned u1 = h32[s1 * 64 + lane];
        unsigned u2 = h32[s2 * 64 + lane];
        unsigned u3 = h32[s3 * 64 + lane];
        ax += bflo(u0) + bflo(u1); ay += bfhi(u0) + bfhi(u1);
        ax += bflo(u2) + bflo(u3); ay += bfhi(u2) + bfhi(u3);
    }
    for (; e < e1; ++e){
        unsigned u0 = h32[ssort[e] * 64 + lane];
        ax += bflo(u0); ay += bfhi(u0);
    }
    z32[n * 64 + lane] = packbf(ax, ay);
}

// C[N,128] = opt_relu_bn(A[N,128]) @ W[128,128] + bias, bf16 MFMA 16x16x32.
// Fused epilogue: column sum/sumsq of fp32 C -> atomicAdd into ostats.
// Block 0 zeroes zstats (stats buffer for the NEXT gemm) if non-null.
template<int TR>
__global__ __launch_bounds__(256) void gemm_k(const unsigned* __restrict__ A32,
                                              const unsigned short* __restrict__ Wtg,
                                              const float* __restrict__ bias,
                                              unsigned short* __restrict__ Cst,
                                              const float* __restrict__ stats,
                                              const float* __restrict__ gma,
                                              const float* __restrict__ bta,
                                              float* __restrict__ ostats,
                                              float* __restrict__ zstats){
    __shared__ __align__(16) unsigned short Wl[128 * 128];  // [j][k] 32KB
    __shared__ __align__(16) unsigned short As[128 * 64];   // [row][k-half] 16KB (reused as f32 scratch)
    __shared__ float sl[128], tl[128];
    int tid = threadIdx.x;
    if (blockIdx.x == 0 && zstats) zstats[tid] = 0.f;
    {
        const uint4* src = (const uint4*)Wtg; uint4* dst = (uint4*)Wl;
        #pragma unroll
        for (int i = 0; i < 8; i++) dst[tid + 256 * i] = src[tid + 256 * i];
    }
    if (TR && tid < 128){
        float mean = stats[tid] * INV_N;
        float q    = stats[128 + tid] * INV_N;
        float inv  = rsqrtf(q - mean * mean + BN_EPS);
        float s    = gma[tid] * inv;
        sl[tid] = s; tl[tid] = bta[tid] - mean * s;
    }
    __syncthreads();

    f32x4 acc[2][8];
    #pragma unroll
    for (int a = 0; a < 2; a++)
        #pragma unroll
        for (int b = 0; b < 8; b++) acc[a][b] = (f32x4){0.f, 0.f, 0.f, 0.f};

    int wv = tid >> 6, lane = tid & 63;
    int rowbase = blockIdx.x * 128;
    int r = tid >> 1, koU = (tid & 1) * 16;

    for (int kh = 0; kh < 2; ++kh){
        if (kh) __syncthreads();
        uint4 v[4];
        int grow = rowbase + r;
        if (grow < NN){
            const uint4* p = (const uint4*)(A32 + grow * 64 + kh * 32 + koU);
            #pragma unroll
            for (int j = 0; j < 4; j++) v[j] = p[j];
        } else {
            #pragma unroll
            for (int j = 0; j < 4; j++) v[j] = make_uint4(0, 0, 0, 0);
        }
        if (TR){
            #pragma unroll
            for (int j = 0; j < 4; j++){
                unsigned* pu = (unsigned*)&v[j];
                #pragma unroll
                for (int c = 0; c < 4; c++){
                    int k = kh * 64 + koU * 2 + j * 8 + c * 2;
                    float f0 = fmaxf(bflo(pu[c]) * sl[k] + tl[k], 0.f);
                    float f1 = fmaxf(bfhi(pu[c]) * sl[k + 1] + tl[k + 1], 0.f);
                    pu[c] = packbf(f0, f1);
                }
            }
        }
        {
            uint4* dst = ((uint4*)As) + r * 8 + (tid & 1) * 4;
            #pragma unroll
            for (int j = 0; j < 4; j++) dst[j] = v[j];
        }
        __syncthreads();
        #pragma unroll
        for (int kc = 0; kc < 2; ++kc){
            int kof = kc * 32 + ((lane >> 4) * 8);
            bf16x8 a0 = ldfrag(&As[(wv * 32 +      (lane & 15)) * 64 + kof]);
            bf16x8 a1 = ldfrag(&As[(wv * 32 + 16 + (lane & 15)) * 64 + kof]);
            int wk = kh * 64 + kof;
            #pragma unroll
            for (int ct = 0; ct < 8; ++ct){
                bf16x8 b = ldfrag(&Wl[(ct * 16 + (lane & 15)) * 128 + wk]);
                acc[0][ct] = __builtin_amdgcn_mfma_f32_16x16x32_bf16(a0, b, acc[0][ct], 0, 0, 0);
                acc[1][ct] = __builtin_amdgcn_mfma_f32_16x16x32_bf16(a1, b, acc[1][ct], 0, 0, 0);
            }
        }
    }
    // epilogue: C/D layout col=lane&15, row=(lane>>4)*4+reg. Store + column stats.
    int cl = lane & 15, rq = lane >> 4;
    float colS[8], colQ[8];
    #pragma unroll
    for (int ct = 0; ct < 8; ++ct){
        float bv = bias[ct * 16 + cl];
        float ps = 0.f, pq = 0.f;
        #pragma unroll
        for (int rt = 0; rt < 2; ++rt){
            #pragma unroll
            for (int rr2 = 0; rr2 < 4; ++rr2){
                int grow = rowbase + wv * 32 + rt * 16 + rq * 4 + rr2;
                if (grow < NN){
                    float val = acc[rt][ct][rr2] + bv;
                    Cst[grow * 128 + ct * 16 + cl] = f2bf(val);
                    ps += val; pq += val * val;
                }
            }
        }
        ps += __shfl_xor(ps, 16); pq += __shfl_xor(pq, 16);
        ps += __shfl_xor(ps, 32); pq += __shfl_xor(pq, 32);
        colS[ct] = ps; colQ[ct] = pq;
    }
    __syncthreads();                       // done with As; reuse as float scratch
    float* sred = (float*)As;              // [0..511]=sums(wv,col), [512..1023]=sumsq
    if (rq == 0){
        #pragma unroll
        for (int ct = 0; ct < 8; ++ct){
            sred[wv * 128 + ct * 16 + cl]       = colS[ct];
            sred[512 + wv * 128 + ct * 16 + cl] = colQ[ct];
        }
    }
    __syncthreads();
    if (tid < 128){
        float s1 = sred[tid] + sred[128 + tid] + sred[256 + tid] + sred[384 + tid];
        float s2 = sred[512 + tid] + sred[640 + tid] + sred[768 + tid] + sred[896 + tid];
        atomicAdd(&ostats[tid], s1);
        atomicAdd(&ostats[128 + tid], s2);
    }
}

// h = relu(bn(z)) (write h) fused with per-graph pooling. One block per graph.
__global__ __launch_bounds__(256) void ewpool_k(const unsigned* __restrict__ z32,
                                                const float* __restrict__ stats,
                                                const float* __restrict__ g,
                                                const float* __restrict__ b,
                                                const int* __restrict__ gstart,
                                                unsigned* __restrict__ h32,
                                                float* __restrict__ outp){
    __shared__ float sd[512];
    int gid = blockIdx.x; int tid = threadIdx.x;
    int c = tid & 63, rs = tid >> 6;
    int c2 = c * 2;
    float m0 = stats[c2] * INV_N,     q0 = stats[128 + c2] * INV_N;
    float inv0 = rsqrtf(q0 - m0 * m0 + BN_EPS);
    float s0 = g[c2] * inv0, t0 = b[c2] - m0 * s0;
    float m1 = stats[c2 + 1] * INV_N, q1 = stats[129 + c2] * INV_N;
    float inv1 = rsqrtf(q1 - m1 * m1 + BN_EPS);
    float s1 = g[c2 + 1] * inv1, t1 = b[c2 + 1] - m1 * s1;
    int s = gstart[gid], e = gstart[gid + 1];
    float a0 = 0.f, a1 = 0.f;
    for (int n = s + rs; n < e; n += 4){
        unsigned u = z32[n * 64 + c];
        float f0 = fmaxf(bflo(u) * s0 + t0, 0.f);
        float f1 = fmaxf(bfhi(u) * s1 + t1, 0.f);
        h32[n * 64 + c] = packbf(f0, f1);
        a0 += f0; a1 += f1;
    }
    sd[tid] = a0; sd[256 + tid] = a1; __syncthreads();
    if (tid < 64){
        float r0 = 0.f, r1 = 0.f;
        #pragma unroll
        for (int k2 = 0; k2 < 4; k2++){ r0 += sd[tid + 64 * k2]; r1 += sd[256 + tid + 64 * k2]; }
        outp[gid * 128 + 2 * tid] = r0; outp[gid * 128 + 2 * tid + 1] = r1;
    }
}

// pooled[0] from fp32 x (exact)
__global__ __launch_bounds__(256) void poolx_k(const float* __restrict__ x,
                                               const int* __restrict__ gstart,
                                               float* __restrict__ outp){
    __shared__ float sd[256];
    int g = blockIdx.x; int tid = threadIdx.x; int c = tid & 127, rs = tid >> 7;
    int s = gstart[g], e = gstart[g + 1];
    float a = 0;
    for (int n = s + rs; n < e; n += 2) a += x[n * 128 + c];
    sd[tid] = a; __syncthreads();
    if (tid < 128) outp[g * 128 + tid] = sd[tid] + sd[tid + 128];
}

// logits = sum_i pooled_i @ fcW_i + fcb_i ; out = log_softmax(logits)
__global__ __launch_bounds__(64) void final_k(const float* __restrict__ pooled,
                                              const float* __restrict__ fcW,
                                              const float* __restrict__ fcb,
                                              float* __restrict__ out){
    int g = blockIdx.x, l = threadIdx.x;
    float p0[5], p1[5];
    #pragma unroll
    for (int i = 0; i < 5; i++){
        p0[i] = pooled[i * GD + g * 128 + l];
        p1[i] = pooled[i * GD + g * 128 + 64 + l];
    }
    float lg[10];
    #pragma unroll
    for (int c2 = 0; c2 < 10; c2++){
        float s = 0;
        #pragma unroll
        for (int i = 0; i < 5; i++){
            s += p0[i] * fcW[(i * 128 + l) * 10 + c2];
            s += p1[i] * fcW[(i * 128 + 64 + l) * 10 + c2];
        }
        #pragma unroll
        for (int off = 32; off >= 1; off >>= 1) s += __shfl_down(s, off);
        lg[c2] = s;
    }
    if (l == 0){
        #pragma unroll
        for (int c2 = 0; c2 < 10; c2++){
            float bs = 0;
            #pragma unroll
            for (int i = 0; i < 5; i++) bs += fcb[i * 10 + c2];
            lg[c2] += bs;
        }
        float mx = lg[0];
        #pragma unroll
        for (int c2 = 1; c2 < 10; c2++) mx = fmaxf(mx, lg[c2]);
        float se = 0;
        #pragma unroll
        for (int c2 = 0; c2 < 10; c2++) se += expf(lg[c2] - mx);
        float lse = mx + logf(se);
        #pragma unroll
        for (int c2 = 0; c2 < 10; c2++) out[g * 10 + c2] = lg[c2] - lse;
    }
}

// ---------------- launch ----------------

extern "C" void kernel_launch(void* const* d_in, const int* in_sizes, int n_in,
                              void* d_out, int out_size, void* d_ws, size_t ws_size,
                              hipStream_t stream){
    (void)in_sizes; (void)n_in; (void)out_size; (void)ws_size;
    const float* x     = (const float*)d_in[0];
    const int*   ei    = (const int*)d_in[1];
    const int*   batch = (const int*)d_in[2];
    const float* cW1   = (const float*)d_in[4];
    const float* cb1   = (const float*)d_in[5];
    const float* cbng  = (const float*)d_in[6];
    const float* cbnb  = (const float*)d_in[7];
    const float* cW2   = (const float*)d_in[8];
    const float* cb2   = (const float*)d_in[9];
    const float* bng   = (const float*)d_in[10];
    const float* bnb   = (const float*)d_in[11];
    const float* fcW   = (const float*)d_in[12];
    const float* fcb   = (const float*)d_in[13];

    char* base = (char*)d_ws;
    size_t off = 0;
    auto alloc = [&](size_t bytes) -> void* {
        void* p = base + off;
        off = (off + bytes + 255) & ~(size_t)255;
        return p;
    };
    unsigned*       hB     = (unsigned*)alloc((size_t)NN * 64 * 4);
    unsigned*       zA     = (unsigned*)alloc((size_t)NN * 64 * 4);
    unsigned*       zB     = (unsigned*)alloc((size_t)NN * 64 * 4);
    unsigned short* Wtall  = (unsigned short*)alloc(8 * 16384 * 2);
    int*            ssort  = (int*)alloc((size_t)EE * 4);
    int*            rp     = (int*)alloc((NN + 1) * 4);
    int*            bsums  = (int*)alloc(256 * 4);
    int*            gstart = (int*)alloc((GG + 1) * 4);
    int*            bucketCur = (int*)alloc(NB * 4);
    // ---- contiguous zero region: cnt, gcnt ----
    int*            cnt    = (int*)alloc(NN * 4);
    int*            gcnt   = (int*)alloc(GG * 4);
    // -------------------------------------------
    float*          pooled = (float*)alloc((size_t)5 * GD * 4);
    float*          stats1 = (float*)alloc(256 * 4);
    float*          stats2 = (float*)alloc(256 * 4);
    unsigned*       binned = zA;   // alias: binned used only before layer loop

    int zwords = (int)(((char*)(gcnt + GG) - (char*)cnt) / 4);

    zero_k<<<(zwords + 255) / 256, 256, 0, stream>>>((float*)cnt, zwords);
    convx_k<<<NN * 64 / 256, 256, 0, stream>>>((const float2*)x, hB);
    wprep_k<<<512, 256, 0, stream>>>(cW1, cW2, Wtall);
    hist_k<<<EE / 256, 256, 0, stream>>>(ei + EE, batch, cnt, gcnt);
    scan1_k<<<49, 256, 0, stream>>>(cnt, rp, bsums);
    scan2_k<<<1, 256, 0, stream>>>(bsums, 49, gcnt, gstart);
    scan3_k<<<(NN + 255) / 256, 256, 0, stream>>>(rp, bsums, bucketCur);
    binA_k<<<(EE + BK_EDGES - 1) / BK_EDGES, 256, 0, stream>>>(ei, ei + EE, bucketCur, binned);
    binB_k<<<NB, 256, 0, stream>>>(binned, rp, ssort);
    poolx_k<<<GG, 256, 0, stream>>>(x, gstart, pooled);

    const int gemmGrid = (NN + 127) / 128;
    for (int i = 0; i < LLAY; i++){
        agg_k<<<NN / 4, 256, 0, stream>>>(hB, rp, ssort, zA, stats1);
        gemm_k<0><<<gemmGrid, 256, 0, stream>>>(zA, Wtall + i * 16384, cb1 + i * 128,
                                                (unsigned short*)zB,
                                                nullptr, nullptr, nullptr, stats1, stats2);
        gemm_k<1><<<gemmGrid, 256, 0, stream>>>(zB, Wtall + (4 + i) * 16384, cb2 + i * 128,
                                                (unsigned short*)zA,
                                                stats1, cbng + i * 128, cbnb + i * 128, stats2, nullptr);
        ewpool_k<<<GG, 256, 0, stream>>>(zA, stats2, bng + i * 128, bnb + i * 128,
                                         gstart, hB, pooled + (size_t)(i + 1) * GD);
    }
    final_k<<<GG, 64, 0, stream>>>(pooled, fcW, fcb, (float*)d_out);
}